// Round 10
// baseline (1111.167 us; speedup 1.0000x reference)
//
#include <hip/hip_runtime.h>

#define NUM_USERS 100000
#define NUM_ITEMS 50000
#define N_NODES   150000   // NUM_USERS + NUM_ITEMS
#define DIM       64
#define NUM_EDGES 2000000
#define NPAD      150016

#define CONV_GRID ((N_NODES + 3) / 4)   // 4 nodes (waves) per 256-thr block

#define NBIN          8
#define COLS_PER_BIN  (N_NODES / NBIN)          // 18750 exact
#define BINCAP        262144                    // per (beh,bin); mean 250K, 26 sigma
#define CAPB          256                       // LDS entries per bin per round

#define SCAN_THREADS 256
#define SCAN_ITEMS   8
#define SCAN_CHUNK   (SCAN_THREADS * SCAN_ITEMS)               // 2048
#define SCAN_NBLK    ((N_NODES + SCAN_CHUNK - 1) / SCAN_CHUNK) // 74

// ---------------------------------------------------------------------------
// PHASE 1: LDS-staged binning by col-range + fused degree histogram.
// Writes to binbuf are contiguous <=2KB bursts claimed once per bin per round
// -> each cache line written once, in full (R8 lesson: write amplification is
// governed by temporal spread of writers per line; fix = full-line bursts).
// Even blocks = cart, odd = rent (R7 lesson: interleave, never tail-append).
__global__ void binphase1_kernel(const int* __restrict__ rowC,
                                 const int* __restrict__ colC,
                                 const int* __restrict__ rowR,
                                 const int* __restrict__ colR,
                                 int* __restrict__ degC,
                                 int* __restrict__ degR,
                                 int* __restrict__ gcnt,     // 16 counters, 64B apart
                                 int2* __restrict__ binbuf) {
    __shared__ int2 buf[NBIN][CAPB];
    __shared__ int  lcnt[NBIN];
    __shared__ int  gpos[NBIN];
    const bool isR = blockIdx.x & 1;
    const int  blk2 = blockIdx.x >> 1;
    const int  nb2  = gridDim.x >> 1;
    const int* row = isR ? rowR : rowC;
    const int* col = isR ? colR : colC;
    int* deg = isR ? degR : degC;
    int2* bb = binbuf + (size_t)(isR ? NBIN : 0) * BINCAP;
    const int gbase = (isR ? NBIN : 0);
    const int tid = threadIdx.x;

    if (tid < NBIN) lcnt[tid] = 0;
    __syncthreads();

    for (int base = blk2 * 256; base < NUM_EDGES; base += nb2 * 256) {
        int e = base + tid;
        if (e < NUM_EDGES) {
            int c = col[e];
            int r = row[e];
            atomicAdd(&deg[c], 1);                 // 150K addrs: low contention
            int b = c / COLS_PER_BIN;
            int p = atomicAdd(&lcnt[b], 1);        // LDS atomic; p < 256 by constr.
            buf[b][p] = make_int2(r, c);
        }
        __syncthreads();
        if (tid < NBIN)
            gpos[tid] = atomicAdd(&gcnt[(gbase + tid) * 16], lcnt[tid]);
        __syncthreads();
        {   // cooperative flush: 32 threads per bin, contiguous burst
            int b = tid >> 5;
            int l = tid & 31;
            int n = lcnt[b];
            int g0 = gpos[b];
            for (int i = l; i < n; i += 32)
                if (g0 + i < BINCAP)
                    bb[(size_t)b * BINCAP + g0 + i] = buf[b][i];
        }
        __syncthreads();
        if (tid < NBIN) lcnt[tid] = 0;
        __syncthreads();
    }
}

// PHASE 2: per-(behavior,bin) ticket scatter. bin = blockIdx&7 -> XCD-affine;
// cursor slice (75KB) + edata slice (~1MB contiguous, since colptr is
// col-ordered) stay in that XCD's L2 -> writes land once.
__global__ void binphase2_kernel(const int2* __restrict__ binbuf,
                                 const int* __restrict__ gcnt,
                                 int* __restrict__ cursC,
                                 int* __restrict__ cursR,
                                 int* __restrict__ edC,
                                 int* __restrict__ edR) {
    const int bin = blockIdx.x & 7;
    const bool isR = (blockIdx.x >> 3) & 1;
    const int sub = blockIdx.x >> 4;
    const int nsub = gridDim.x >> 4;
    int cnt = gcnt[((isR ? NBIN : 0) + bin) * 16];
    if (cnt > BINCAP) cnt = BINCAP;
    const int2* src = binbuf + (size_t)((isR ? NBIN : 0) + bin) * BINCAP;
    int* curs = isR ? cursR : cursC;
    int* ed   = isR ? edR  : edC;
    int stride = nsub * 256;
    for (int i = sub * 256 + (int)threadIdx.x; i < cnt; i += stride) {
        int2 rc = src[i];
        int p = atomicAdd(&curs[rc.y], 1);
        ed[p] = rc.x;
    }
}

// dinv for both behaviors
__global__ void dinv2_kernel(const int* __restrict__ degC,
                             const int* __restrict__ degR,
                             float* __restrict__ dinvC,
                             float* __restrict__ dinvR) {
    int stride = gridDim.x * blockDim.x;
    for (int i = blockIdx.x * blockDim.x + threadIdx.x; i < N_NODES; i += stride) {
        float dc = (float)degC[i];
        float dr = (float)degR[i];
        dinvC[i] = (dc > 0.0f) ? (1.0f / sqrtf(dc)) : 0.0f;
        dinvR[i] = (dr > 0.0f) ? (1.0f / sqrtf(dr)) : 0.0f;
    }
}

// ---- exclusive scans (both behaviors fused; C = blocks [0,74), R = [74,148))
__global__ void scanA2_kernel(const int* __restrict__ degC,
                              const int* __restrict__ degR,
                              int* __restrict__ cptrC,
                              int* __restrict__ cptrR,
                              int* __restrict__ bsum) {
    __shared__ int s[SCAN_THREADS];
    bool isR = blockIdx.x >= SCAN_NBLK;
    int b = isR ? (int)blockIdx.x - SCAN_NBLK : (int)blockIdx.x;
    const int* deg = isR ? degR : degC;
    int* cptr = isR ? cptrR : cptrC;
    int t = threadIdx.x;
    int base = b * SCAN_CHUNK + t * SCAN_ITEMS;
    int items[SCAN_ITEMS];
    int mysum = 0;
    #pragma unroll
    for (int j = 0; j < SCAN_ITEMS; ++j) {
        int idx = base + j;
        items[j] = (idx < N_NODES) ? deg[idx] : 0;
        mysum += items[j];
    }
    s[t] = mysum;
    __syncthreads();
    for (int off = 1; off < SCAN_THREADS; off <<= 1) {
        int v = (t >= off) ? s[t - off] : 0;
        __syncthreads();
        s[t] += v;
        __syncthreads();
    }
    int excl = s[t] - mysum;
    if (t == SCAN_THREADS - 1) bsum[blockIdx.x] = s[t];
    int run = excl;
    #pragma unroll
    for (int j = 0; j < SCAN_ITEMS; ++j) {
        int idx = base + j;
        if (idx < N_NODES) cptr[idx] = run;
        run += items[j];
    }
}

__global__ void scanB2_kernel(const int* __restrict__ bsum,
                              int* __restrict__ boff,
                              int* __restrict__ cptrC,
                              int* __restrict__ cptrR) {
    if (threadIdx.x == 0) {
        int run = 0;
        for (int b = 0; b < SCAN_NBLK; ++b) { boff[b] = run; run += bsum[b]; }
        cptrC[N_NODES] = run;
    } else if (threadIdx.x == 1) {
        int run = 0;
        for (int b = SCAN_NBLK; b < 2 * SCAN_NBLK; ++b) { boff[b] = run; run += bsum[b]; }
        cptrR[N_NODES] = run;
    }
}

__global__ void scanC2_kernel(int* __restrict__ cptrC,
                              int* __restrict__ cptrR,
                              int* __restrict__ cursC,
                              int* __restrict__ cursR,
                              const int* __restrict__ boff) {
    bool isR = blockIdx.x >= SCAN_NBLK;
    int b = isR ? (int)blockIdx.x - SCAN_NBLK : (int)blockIdx.x;
    int* cptr = isR ? cptrR : cptrC;
    int* curs = isR ? cursR : cursC;
    int off = boff[blockIdx.x];
    int t = threadIdx.x;
    int base = b * SCAN_CHUNK + t * SCAN_ITEMS;
    #pragma unroll
    for (int j = 0; j < SCAN_ITEMS; ++j) {
        int idx = base + j;
        if (idx < N_NODES) {
            int v = cptr[idx] + off;
            cptr[idx] = v;
            curs[idx] = v;
        }
    }
}

// XS[i] = dinvC[node] * x0[i]
__global__ void prescale_kernel(const float4* __restrict__ ue,
                                const float4* __restrict__ ie,
                                const float* __restrict__ dinvC,
                                float4* __restrict__ xs) {
    int stride = gridDim.x * blockDim.x;
    const int n4 = N_NODES * 16;
    for (int i = blockIdx.x * blockDim.x + threadIdx.x; i < n4; i += stride) {
        int node = i >> 4;
        float d = dinvC[node];
        float4 v = (node < NUM_USERS) ? ue[i] : ie[i - NUM_USERS * 16];
        xs[i] = make_float4(d * v.x, d * v.y, d * v.z, d * v.w);
    }
}

// ---------------------------------------------------------------------------
// CSR gather conv (R8-verified): pure unweighted sum of pre-scaled rows,
// epilogue x dinv[node]. Wave = 1 node; 8 groups x 8 lanes, 8 edges in flight.
template <int MODE>
__device__ __forceinline__ void conv_body(int blk,
                                          const float4* __restrict__ xin,
                                          const int* __restrict__ colptr,
                                          const int* __restrict__ edata,
                                          const float* __restrict__ dinv,
                                          float4* o1,
                                          float4* __restrict__ o2,
                                          const float4* __restrict__ a0,
                                          const float4* __restrict__ a1,
                                          const float4* __restrict__ a2,
                                          const float4* __restrict__ ue,
                                          const float4* __restrict__ ie) {
    int lane = threadIdx.x & 63;
    int node = blk * 4 + (threadIdx.x >> 6);
    if (node >= N_NODES) return;
    int grp = lane >> 3;
    int l8  = lane & 7;
    int s = colptr[node];
    int t = colptr[node + 1];
    float4 acc0 = make_float4(0.f, 0.f, 0.f, 0.f);
    float4 acc1 = make_float4(0.f, 0.f, 0.f, 0.f);
    for (int e = s + grp; e < t; e += 8) {
        int r = edata[e];
        const float4* xp = xin + (size_t)r * 16 + l8 * 2;
        float4 v0 = xp[0];
        float4 v1 = xp[1];
        acc0.x += v0.x; acc0.y += v0.y; acc0.z += v0.z; acc0.w += v0.w;
        acc1.x += v1.x; acc1.y += v1.y; acc1.z += v1.z; acc1.w += v1.w;
    }
    #pragma unroll
    for (int m = 8; m <= 32; m <<= 1) {
        acc0.x += __shfl_xor(acc0.x, m); acc0.y += __shfl_xor(acc0.y, m);
        acc0.z += __shfl_xor(acc0.z, m); acc0.w += __shfl_xor(acc0.w, m);
        acc1.x += __shfl_xor(acc1.x, m); acc1.y += __shfl_xor(acc1.y, m);
        acc1.z += __shfl_xor(acc1.z, m); acc1.w += __shfl_xor(acc1.w, m);
    }
    if (grp == 0) {
        float dc = dinv[node];
        int o = node * 16 + l8 * 2;
        if (MODE == 0) {
            float d2 = dc * dc;
            o1[o]     = make_float4(dc * acc0.x, dc * acc0.y, dc * acc0.z, dc * acc0.w);
            o1[o + 1] = make_float4(dc * acc1.x, dc * acc1.y, dc * acc1.z, dc * acc1.w);
            o2[o]     = make_float4(d2 * acc0.x, d2 * acc0.y, d2 * acc0.z, d2 * acc0.w);
            o2[o + 1] = make_float4(d2 * acc1.x, d2 * acc1.y, d2 * acc1.z, d2 * acc1.w);
        } else if (MODE == 1) {
            const float sc = 1.0f / 3.0f;
            float4 x0, x1;
            if (node < NUM_USERS) { x0 = ue[o]; x1 = ue[o + 1]; }
            else { x0 = ie[o - NUM_USERS * 16]; x1 = ie[o + 1 - NUM_USERS * 16]; }
            float4 h0 = a1[o], h1 = a1[o + 1];
            o1[o]     = make_float4((x0.x + h0.x + dc * acc0.x) * sc,
                                    (x0.y + h0.y + dc * acc0.y) * sc,
                                    (x0.z + h0.z + dc * acc0.z) * sc,
                                    (x0.w + h0.w + dc * acc0.w) * sc);
            o1[o + 1] = make_float4((x1.x + h1.x + dc * acc1.x) * sc,
                                    (x1.y + h1.y + dc * acc1.y) * sc,
                                    (x1.z + h1.z + dc * acc1.z) * sc,
                                    (x1.w + h1.w + dc * acc1.w) * sc);
        } else {
            const float sc = 1.0f / 3.0f;
            float4 p0 = a0[o], p1 = a0[o + 1];
            float4 h0 = o1[o], h1 = o1[o + 1];    // H1r parked in d_out
            float4 g0 = a2[o], g1 = a2[o + 1];
            o1[o]     = make_float4(g0.x + (p0.x + h0.x + dc * acc0.x) * sc,
                                    g0.y + (p0.y + h0.y + dc * acc0.y) * sc,
                                    g0.z + (p0.z + h0.z + dc * acc0.z) * sc,
                                    g0.w + (p0.w + h0.w + dc * acc0.w) * sc);
            o1[o + 1] = make_float4(g1.x + (p1.x + h1.x + dc * acc1.x) * sc,
                                    g1.y + (p1.y + h1.y + dc * acc1.y) * sc,
                                    g1.z + (p1.z + h1.z + dc * acc1.z) * sc,
                                    g1.w + (p1.w + h1.w + dc * acc1.w) * sc);
        }
    }
}

__global__ void conv1_kernel(const float4* __restrict__ xin,
                             const int* __restrict__ colptr,
                             const int* __restrict__ edata,
                             const float* __restrict__ dinv,
                             float4* __restrict__ oH,
                             float4* __restrict__ oHS) {
    conv_body<0>(blockIdx.x, xin, colptr, edata, dinv, oH, oHS,
                 nullptr, nullptr, nullptr, nullptr, nullptr);
}

__global__ void conv2c_kernel(const float4* __restrict__ xin,
                              const int* __restrict__ colptr,
                              const int* __restrict__ edata,
                              const float* __restrict__ dinv,
                              const float4* __restrict__ h1,
                              const float4* __restrict__ ue,
                              const float4* __restrict__ ie,
                              float4* __restrict__ cart) {
    conv_body<1>(blockIdx.x, xin, colptr, edata, dinv, cart, nullptr,
                 nullptr, h1, nullptr, ue, ie);
}

__global__ void conv2r_kernel(const float4* __restrict__ xin,
                              const int* __restrict__ colptr,
                              const int* __restrict__ edata,
                              const float* __restrict__ dinv,
                              const float4* __restrict__ x2,
                              const float4* __restrict__ cart,
                              float4* outp) {
    conv_body<2>(blockIdx.x, xin, colptr, edata, dinv, outp, nullptr,
                 x2, nullptr, cart, nullptr, nullptr);
}

// Wt[k][j] = W[j][k]
__global__ void transpose_w_kernel(const float* __restrict__ Wu,
                                   const float* __restrict__ Wi,
                                   float* __restrict__ WtU,
                                   float* __restrict__ WtI) {
    for (int t = threadIdx.x; t < DIM * DIM; t += blockDim.x) {
        int j = t >> 6, k = t & 63;
        WtU[k * DIM + j] = Wu[t];
        WtI[k * DIM + j] = Wi[t];
    }
}

// dst = src @ Wt (per-row user/item); dsts = dinvR[i] * dst
__global__ void matmul2_kernel(const float* __restrict__ src,
                               const float* __restrict__ WtU,
                               const float* __restrict__ WtI,
                               const float* __restrict__ dinvR,
                               float* __restrict__ dst,
                               float* __restrict__ dsts) {
    __shared__ float rows[4][DIM];
    int lane = threadIdx.x & 63;
    int g = threadIdx.x >> 6;
    int totalGroups = N_NODES / 4;
    for (int blk = blockIdx.x; blk < totalGroups; blk += gridDim.x) {
        int i = blk * 4 + g;
        rows[g][lane] = src[(size_t)i * DIM + lane];
        __syncthreads();
        const float* Wt = (i < NUM_USERS) ? WtU : WtI;
        float acc = 0.0f;
        #pragma unroll
        for (int k = 0; k < DIM; ++k)
            acc = fmaf(rows[g][k], Wt[k * DIM + lane], acc);
        dst[(size_t)i * DIM + lane]  = acc;
        dsts[(size_t)i * DIM + lane] = dinvR[i] * acc;
        __syncthreads();
    }
}

// ---------------------------------------------------------------------------
extern "C" void kernel_launch(void* const* d_in, const int* in_sizes, int n_in,
                              void* d_out, int out_size, void* d_ws, size_t ws_size,
                              hipStream_t stream) {
    const float* user_emb = (const float*)d_in[0];
    const float* item_emb = (const float*)d_in[1];
    const float* W_user   = (const float*)d_in[2];
    const float* W_item   = (const float*)d_in[3];
    const int*   ec       = (const int*)d_in[4];
    const int*   er       = (const int*)d_in[5];
    const int* cart_row = ec;
    const int* cart_col = ec + NUM_EDGES;
    const int* rent_row = er;
    const int* rent_col = er + NUM_EDGES;
    float* out = (float*)d_out;

    const size_t NV = (size_t)N_NODES * DIM;       // 9.6M floats
    float* ws    = (float*)d_ws;
    float* A     = ws;                  // XS, then X2 after matmul
    float* B     = A + NV;              // H1 (cart), then XS2
    float* C     = B + NV;              // HS (cart), then HSr (rent)
    float* D     = C + NV;              // CART; BINBUF overlaid until phase2 done
    float* DINVC = D + NV;
    float* DINVR = DINVC + NPAD;
    int*   DEGC  = (int*)(DINVR + NPAD);
    int*   DEGR  = DEGC + NPAD;
    int*   GCNT  = DEGR + NPAD;         // 16 counters x 16-int stride = 256 ints
    int*   CPTRC = GCNT + 256;
    int*   CURSC = CPTRC + NPAD;
    int*   CPTRR = CURSC + NPAD;
    int*   CURSR = CPTRR + NPAD;
    int*   BSUM  = CURSR + NPAD;
    int*   BOFF  = BSUM + 256;
    float* WtU   = (float*)(BOFF + 256);
    float* WtI   = WtU + DIM * DIM;
    int*   EDC   = (int*)(WtI + DIM * DIM);   // 2M int = 8 MB
    int*   EDR   = EDC + NUM_EDGES;
    int2*  BINBUF= (int2*)D;                  // 16 x 262144 x 8B = 33.5MB < 38.4MB

    const int BLOCKS = 2048, THREADS = 256;

    hipMemsetAsync(DEGC, 0, (2 * NPAD + 256) * sizeof(int), stream);
    transpose_w_kernel<<<1, 256, 0, stream>>>(W_user, W_item, WtU, WtI);

    // phase 1: bin edges by col-range + degree histogram (both behaviors)
    binphase1_kernel<<<2048, 256, 0, stream>>>(cart_row, cart_col,
                                               rent_row, rent_col,
                                               DEGC, DEGR, GCNT, BINBUF);
    // dinv + colptr scans
    dinv2_kernel<<<(N_NODES + 255) / 256, 256, 0, stream>>>(DEGC, DEGR, DINVC, DINVR);
    scanA2_kernel<<<2 * SCAN_NBLK, SCAN_THREADS, 0, stream>>>(DEGC, DEGR, CPTRC, CPTRR, BSUM);
    scanB2_kernel<<<1, 64, 0, stream>>>(BSUM, BOFF, CPTRC, CPTRR);
    scanC2_kernel<<<2 * SCAN_NBLK, SCAN_THREADS, 0, stream>>>(CPTRC, CPTRR, CURSC, CURSR, BOFF);

    // phase 2: XCD-affine ticket scatter (both behaviors)
    binphase2_kernel<<<2048, 256, 0, stream>>>(BINBUF, GCNT, CURSC, CURSR, EDC, EDR);

    // XS = dinvC * concat(user_emb, item_emb)
    prescale_kernel<<<BLOCKS, THREADS, 0, stream>>>((const float4*)user_emb,
                                                    (const float4*)item_emb,
                                                    DINVC, (float4*)A);

    // cart: H1 (B), HS = dinvC*H1 (C)
    conv1_kernel<<<CONV_GRID, 256, 0, stream>>>((const float4*)A, CPTRC, EDC,
                                                DINVC, (float4*)B, (float4*)C);
    // CART = (X + H1 + conv(HS)) / 3   (D -- BINBUF dead from here)
    conv2c_kernel<<<CONV_GRID, 256, 0, stream>>>((const float4*)C, CPTRC, EDC,
                                                 DINVC, (const float4*)B,
                                                 (const float4*)user_emb,
                                                 (const float4*)item_emb,
                                                 (float4*)D);

    // projection: X2 = CART @ W^T (A), XS2 = dinvR*X2 (B)
    matmul2_kernel<<<BLOCKS, THREADS, 0, stream>>>(D, WtU, WtI, DINVR, A, B);

    // rent: H1r -> d_out (parked), HSr -> C
    conv1_kernel<<<CONV_GRID, 256, 0, stream>>>((const float4*)B, CPTRR, EDR,
                                                DINVR, (float4*)out, (float4*)C);
    // out = CART + (X2 + H1r + conv(HSr)) / 3
    conv2r_kernel<<<CONV_GRID, 256, 0, stream>>>((const float4*)C, CPTRR, EDR,
                                                 DINVR, (const float4*)A,
                                                 (const float4*)D, (float4*)out);
}

// Round 11
// 1110.288 us; speedup vs baseline: 1.0008x; 1.0008x over previous
//
#include <hip/hip_runtime.h>

#define NUM_USERS 100000
#define NUM_ITEMS 50000
#define N_NODES   150000   // NUM_USERS + NUM_ITEMS
#define DIM       64
#define NUM_EDGES 2000000
#define NPAD      150016

#define CONV_GRID ((N_NODES + 3) / 4)   // 4 nodes (waves) per 256-thr block

#define NBIN          8
#define COLS_PER_BIN  (N_NODES / NBIN)   // 18750 exact
#define P1_BLKS_PER_B 256                // blocks per behavior in phase 1
#define CAP           1152               // per (block,bin); mean 977, +6 sigma
// binbuf total: 2*256*8*1152 int2 = 37.75 MB  (overlaid on D region, 38.4 MB)

#define SCAN_THREADS 256
#define SCAN_ITEMS   8
#define SCAN_CHUNK   (SCAN_THREADS * SCAN_ITEMS)               // 2048
#define SCAN_NBLK    ((N_NODES + SCAN_CHUNK - 1) / SCAN_CHUNK) // 74

// ---------------------------------------------------------------------------
// PHASE 1 v2: ballot-binning into per-BLOCK private regions + fused degree
// histogram. R10 lessons: (a) 8 LDS counters hit by all 256 threads serialize
// -> claim per-wave via ballot (8 LDS atomics/wave); (b) bursts claimed by
// global counter interleave blocks on the same line -> per-block PRIVATE
// regions give every cache line exactly one writer block (amplification ~1).
// Even blocks = cart, odd = rent (R7 lesson: interleave, never tail-append).
__global__ void binphase1_kernel(const int* __restrict__ rowC,
                                 const int* __restrict__ colC,
                                 const int* __restrict__ rowR,
                                 const int* __restrict__ colR,
                                 int* __restrict__ degC,
                                 int* __restrict__ degR,
                                 int* __restrict__ segcnt,   // [2*256][8]
                                 int2* __restrict__ binbuf) {
    __shared__ int lcnt[NBIN];
    const bool isR  = blockIdx.x & 1;
    const int  blk2 = blockIdx.x >> 1;            // 0..255
    const int  tid  = threadIdx.x;
    const int  lane = tid & 63;
    const int* row = isR ? rowR : rowC;
    const int* col = isR ? colR : colC;
    int* deg = isR ? degR : degC;
    const int regidx = (isR ? P1_BLKS_PER_B : 0) + blk2;
    int2* myreg = binbuf + (size_t)regidx * NBIN * CAP;

    if (tid < NBIN) lcnt[tid] = 0;
    __syncthreads();

    const int stride = P1_BLKS_PER_B * 256;       // 65536
    for (int e = blk2 * 256 + tid; e < NUM_EDGES; e += stride) {
        int c = col[e];
        int r = row[e];
        atomicAdd(&deg[c], 1);                    // 150K addrs: low contention
        int b = c / COLS_PER_BIN;                 // 0..7
        // wave-level claim: 8 ballots -> per-lane rank + per-bin count
        unsigned long long masks[NBIN];
        #pragma unroll
        for (int k = 0; k < NBIN; ++k) masks[k] = __ballot(b == k);
        int rank = __popcll(masks[b] & ((1ULL << lane) - 1ULL));
        int old = 0;
        if (lane < NBIN) old = atomicAdd(&lcnt[lane], (int)__popcll(masks[lane]));
        int base = __shfl(old, b);
        int pos = base + rank;
        if (pos < CAP)                             // 6-sigma headroom
            myreg[b * CAP + pos] = make_int2(r, c);
    }
    __syncthreads();
    if (tid < NBIN) {
        int v = lcnt[tid];
        segcnt[regidx * NBIN + tid] = (v < CAP) ? v : CAP;
    }
}

// PHASE 2 v2: 32 blocks, 2 per (behavior,bin). Each block streams its half of
// the bin's segments (~1MB) and ticket-scatters into the bin's contiguous
// ~1MB edata window -> <=2 writer blocks per line, L2-resident, ~1x writeback.
__global__ void binphase2_kernel(const int2* __restrict__ binbuf,
                                 const int* __restrict__ segcnt,
                                 int* __restrict__ cursC,
                                 int* __restrict__ cursR,
                                 int* __restrict__ edC,
                                 int* __restrict__ edR) {
    const int bin  = blockIdx.x & 7;
    const bool isR = (blockIdx.x >> 3) & 1;
    const int half = blockIdx.x >> 4;             // 0..1
    int* curs = isR ? cursR : cursC;
    int* ed   = isR ? edR  : edC;
    const int sb0 = half * (P1_BLKS_PER_B / 2);
    for (int sb = sb0; sb < sb0 + P1_BLKS_PER_B / 2; ++sb) {
        const int regidx = (isR ? P1_BLKS_PER_B : 0) + sb;
        int cnt = segcnt[regidx * NBIN + bin];
        const int2* src = binbuf + ((size_t)regidx * NBIN + bin) * CAP;
        for (int i = threadIdx.x; i < cnt; i += blockDim.x) {
            int2 rc = src[i];
            int p = atomicAdd(&curs[rc.y], 1);
            ed[p] = rc.x;
        }
    }
}

// dinv for both behaviors
__global__ void dinv2_kernel(const int* __restrict__ degC,
                             const int* __restrict__ degR,
                             float* __restrict__ dinvC,
                             float* __restrict__ dinvR) {
    int stride = gridDim.x * blockDim.x;
    for (int i = blockIdx.x * blockDim.x + threadIdx.x; i < N_NODES; i += stride) {
        float dc = (float)degC[i];
        float dr = (float)degR[i];
        dinvC[i] = (dc > 0.0f) ? (1.0f / sqrtf(dc)) : 0.0f;
        dinvR[i] = (dr > 0.0f) ? (1.0f / sqrtf(dr)) : 0.0f;
    }
}

// ---- exclusive scans (both behaviors fused; C = blocks [0,74), R = [74,148))
__global__ void scanA2_kernel(const int* __restrict__ degC,
                              const int* __restrict__ degR,
                              int* __restrict__ cptrC,
                              int* __restrict__ cptrR,
                              int* __restrict__ bsum) {
    __shared__ int s[SCAN_THREADS];
    bool isR = blockIdx.x >= SCAN_NBLK;
    int b = isR ? (int)blockIdx.x - SCAN_NBLK : (int)blockIdx.x;
    const int* deg = isR ? degR : degC;
    int* cptr = isR ? cptrR : cptrC;
    int t = threadIdx.x;
    int base = b * SCAN_CHUNK + t * SCAN_ITEMS;
    int items[SCAN_ITEMS];
    int mysum = 0;
    #pragma unroll
    for (int j = 0; j < SCAN_ITEMS; ++j) {
        int idx = base + j;
        items[j] = (idx < N_NODES) ? deg[idx] : 0;
        mysum += items[j];
    }
    s[t] = mysum;
    __syncthreads();
    for (int off = 1; off < SCAN_THREADS; off <<= 1) {
        int v = (t >= off) ? s[t - off] : 0;
        __syncthreads();
        s[t] += v;
        __syncthreads();
    }
    int excl = s[t] - mysum;
    if (t == SCAN_THREADS - 1) bsum[blockIdx.x] = s[t];
    int run = excl;
    #pragma unroll
    for (int j = 0; j < SCAN_ITEMS; ++j) {
        int idx = base + j;
        if (idx < N_NODES) cptr[idx] = run;
        run += items[j];
    }
}

__global__ void scanB2_kernel(const int* __restrict__ bsum,
                              int* __restrict__ boff,
                              int* __restrict__ cptrC,
                              int* __restrict__ cptrR) {
    if (threadIdx.x == 0) {
        int run = 0;
        for (int b = 0; b < SCAN_NBLK; ++b) { boff[b] = run; run += bsum[b]; }
        cptrC[N_NODES] = run;
    } else if (threadIdx.x == 1) {
        int run = 0;
        for (int b = SCAN_NBLK; b < 2 * SCAN_NBLK; ++b) { boff[b] = run; run += bsum[b]; }
        cptrR[N_NODES] = run;
    }
}

__global__ void scanC2_kernel(int* __restrict__ cptrC,
                              int* __restrict__ cptrR,
                              int* __restrict__ cursC,
                              int* __restrict__ cursR,
                              const int* __restrict__ boff) {
    bool isR = blockIdx.x >= SCAN_NBLK;
    int b = isR ? (int)blockIdx.x - SCAN_NBLK : (int)blockIdx.x;
    int* cptr = isR ? cptrR : cptrC;
    int* curs = isR ? cursR : cursC;
    int off = boff[blockIdx.x];
    int t = threadIdx.x;
    int base = b * SCAN_CHUNK + t * SCAN_ITEMS;
    #pragma unroll
    for (int j = 0; j < SCAN_ITEMS; ++j) {
        int idx = base + j;
        if (idx < N_NODES) {
            int v = cptr[idx] + off;
            cptr[idx] = v;
            curs[idx] = v;
        }
    }
}

// XS[i] = dinvC[node] * x0[i]
__global__ void prescale_kernel(const float4* __restrict__ ue,
                                const float4* __restrict__ ie,
                                const float* __restrict__ dinvC,
                                float4* __restrict__ xs) {
    int stride = gridDim.x * blockDim.x;
    const int n4 = N_NODES * 16;
    for (int i = blockIdx.x * blockDim.x + threadIdx.x; i < n4; i += stride) {
        int node = i >> 4;
        float d = dinvC[node];
        float4 v = (node < NUM_USERS) ? ue[i] : ie[i - NUM_USERS * 16];
        xs[i] = make_float4(d * v.x, d * v.y, d * v.z, d * v.w);
    }
}

// ---------------------------------------------------------------------------
// CSR gather conv (R8-verified): pure unweighted sum of pre-scaled rows,
// epilogue x dinv[node]. Wave = 1 node; 8 groups x 8 lanes, 8 edges in flight.
template <int MODE>
__device__ __forceinline__ void conv_body(int blk,
                                          const float4* __restrict__ xin,
                                          const int* __restrict__ colptr,
                                          const int* __restrict__ edata,
                                          const float* __restrict__ dinv,
                                          float4* o1,
                                          float4* __restrict__ o2,
                                          const float4* __restrict__ a0,
                                          const float4* __restrict__ a1,
                                          const float4* __restrict__ a2,
                                          const float4* __restrict__ ue,
                                          const float4* __restrict__ ie) {
    int lane = threadIdx.x & 63;
    int node = blk * 4 + (threadIdx.x >> 6);
    if (node >= N_NODES) return;
    int grp = lane >> 3;
    int l8  = lane & 7;
    int s = colptr[node];
    int t = colptr[node + 1];
    float4 acc0 = make_float4(0.f, 0.f, 0.f, 0.f);
    float4 acc1 = make_float4(0.f, 0.f, 0.f, 0.f);
    for (int e = s + grp; e < t; e += 8) {
        int r = edata[e];
        const float4* xp = xin + (size_t)r * 16 + l8 * 2;
        float4 v0 = xp[0];
        float4 v1 = xp[1];
        acc0.x += v0.x; acc0.y += v0.y; acc0.z += v0.z; acc0.w += v0.w;
        acc1.x += v1.x; acc1.y += v1.y; acc1.z += v1.z; acc1.w += v1.w;
    }
    #pragma unroll
    for (int m = 8; m <= 32; m <<= 1) {
        acc0.x += __shfl_xor(acc0.x, m); acc0.y += __shfl_xor(acc0.y, m);
        acc0.z += __shfl_xor(acc0.z, m); acc0.w += __shfl_xor(acc0.w, m);
        acc1.x += __shfl_xor(acc1.x, m); acc1.y += __shfl_xor(acc1.y, m);
        acc1.z += __shfl_xor(acc1.z, m); acc1.w += __shfl_xor(acc1.w, m);
    }
    if (grp == 0) {
        float dc = dinv[node];
        int o = node * 16 + l8 * 2;
        if (MODE == 0) {
            float d2 = dc * dc;
            o1[o]     = make_float4(dc * acc0.x, dc * acc0.y, dc * acc0.z, dc * acc0.w);
            o1[o + 1] = make_float4(dc * acc1.x, dc * acc1.y, dc * acc1.z, dc * acc1.w);
            o2[o]     = make_float4(d2 * acc0.x, d2 * acc0.y, d2 * acc0.z, d2 * acc0.w);
            o2[o + 1] = make_float4(d2 * acc1.x, d2 * acc1.y, d2 * acc1.z, d2 * acc1.w);
        } else if (MODE == 1) {
            const float sc = 1.0f / 3.0f;
            float4 x0, x1;
            if (node < NUM_USERS) { x0 = ue[o]; x1 = ue[o + 1]; }
            else { x0 = ie[o - NUM_USERS * 16]; x1 = ie[o + 1 - NUM_USERS * 16]; }
            float4 h0 = a1[o], h1 = a1[o + 1];
            o1[o]     = make_float4((x0.x + h0.x + dc * acc0.x) * sc,
                                    (x0.y + h0.y + dc * acc0.y) * sc,
                                    (x0.z + h0.z + dc * acc0.z) * sc,
                                    (x0.w + h0.w + dc * acc0.w) * sc);
            o1[o + 1] = make_float4((x1.x + h1.x + dc * acc1.x) * sc,
                                    (x1.y + h1.y + dc * acc1.y) * sc,
                                    (x1.z + h1.z + dc * acc1.z) * sc,
                                    (x1.w + h1.w + dc * acc1.w) * sc);
        } else {
            const float sc = 1.0f / 3.0f;
            float4 p0 = a0[o], p1 = a0[o + 1];
            float4 h0 = o1[o], h1 = o1[o + 1];    // H1r parked in d_out
            float4 g0 = a2[o], g1 = a2[o + 1];
            o1[o]     = make_float4(g0.x + (p0.x + h0.x + dc * acc0.x) * sc,
                                    g0.y + (p0.y + h0.y + dc * acc0.y) * sc,
                                    g0.z + (p0.z + h0.z + dc * acc0.z) * sc,
                                    g0.w + (p0.w + h0.w + dc * acc0.w) * sc);
            o1[o + 1] = make_float4(g1.x + (p1.x + h1.x + dc * acc1.x) * sc,
                                    g1.y + (p1.y + h1.y + dc * acc1.y) * sc,
                                    g1.z + (p1.z + h1.z + dc * acc1.z) * sc,
                                    g1.w + (p1.w + h1.w + dc * acc1.w) * sc);
        }
    }
}

__global__ void conv1_kernel(const float4* __restrict__ xin,
                             const int* __restrict__ colptr,
                             const int* __restrict__ edata,
                             const float* __restrict__ dinv,
                             float4* __restrict__ oH,
                             float4* __restrict__ oHS) {
    conv_body<0>(blockIdx.x, xin, colptr, edata, dinv, oH, oHS,
                 nullptr, nullptr, nullptr, nullptr, nullptr);
}

__global__ void conv2c_kernel(const float4* __restrict__ xin,
                              const int* __restrict__ colptr,
                              const int* __restrict__ edata,
                              const float* __restrict__ dinv,
                              const float4* __restrict__ h1,
                              const float4* __restrict__ ue,
                              const float4* __restrict__ ie,
                              float4* __restrict__ cart) {
    conv_body<1>(blockIdx.x, xin, colptr, edata, dinv, cart, nullptr,
                 nullptr, h1, nullptr, ue, ie);
}

__global__ void conv2r_kernel(const float4* __restrict__ xin,
                              const int* __restrict__ colptr,
                              const int* __restrict__ edata,
                              const float* __restrict__ dinv,
                              const float4* __restrict__ x2,
                              const float4* __restrict__ cart,
                              float4* outp) {
    conv_body<2>(blockIdx.x, xin, colptr, edata, dinv, outp, nullptr,
                 x2, nullptr, cart, nullptr, nullptr);
}

// Wt[k][j] = W[j][k]
__global__ void transpose_w_kernel(const float* __restrict__ Wu,
                                   const float* __restrict__ Wi,
                                   float* __restrict__ WtU,
                                   float* __restrict__ WtI) {
    for (int t = threadIdx.x; t < DIM * DIM; t += blockDim.x) {
        int j = t >> 6, k = t & 63;
        WtU[k * DIM + j] = Wu[t];
        WtI[k * DIM + j] = Wi[t];
    }
}

// dst = src @ Wt (per-row user/item); dsts = dinvR[i] * dst
__global__ void matmul2_kernel(const float* __restrict__ src,
                               const float* __restrict__ WtU,
                               const float* __restrict__ WtI,
                               const float* __restrict__ dinvR,
                               float* __restrict__ dst,
                               float* __restrict__ dsts) {
    __shared__ float rows[4][DIM];
    int lane = threadIdx.x & 63;
    int g = threadIdx.x >> 6;
    int totalGroups = N_NODES / 4;
    for (int blk = blockIdx.x; blk < totalGroups; blk += gridDim.x) {
        int i = blk * 4 + g;
        rows[g][lane] = src[(size_t)i * DIM + lane];
        __syncthreads();
        const float* Wt = (i < NUM_USERS) ? WtU : WtI;
        float acc = 0.0f;
        #pragma unroll
        for (int k = 0; k < DIM; ++k)
            acc = fmaf(rows[g][k], Wt[k * DIM + lane], acc);
        dst[(size_t)i * DIM + lane]  = acc;
        dsts[(size_t)i * DIM + lane] = dinvR[i] * acc;
        __syncthreads();
    }
}

// ---------------------------------------------------------------------------
extern "C" void kernel_launch(void* const* d_in, const int* in_sizes, int n_in,
                              void* d_out, int out_size, void* d_ws, size_t ws_size,
                              hipStream_t stream) {
    const float* user_emb = (const float*)d_in[0];
    const float* item_emb = (const float*)d_in[1];
    const float* W_user   = (const float*)d_in[2];
    const float* W_item   = (const float*)d_in[3];
    const int*   ec       = (const int*)d_in[4];
    const int*   er       = (const int*)d_in[5];
    const int* cart_row = ec;
    const int* cart_col = ec + NUM_EDGES;
    const int* rent_row = er;
    const int* rent_col = er + NUM_EDGES;
    float* out = (float*)d_out;

    const size_t NV = (size_t)N_NODES * DIM;       // 9.6M floats
    float* ws    = (float*)d_ws;
    float* A     = ws;                  // XS, then X2 after matmul
    float* B     = A + NV;              // H1 (cart), then XS2
    float* C     = B + NV;              // HS (cart), then HSr (rent)
    float* D     = C + NV;              // CART; BINBUF overlaid until phase2 done
    float* DINVC = D + NV;
    float* DINVR = DINVC + NPAD;
    int*   DEGC  = (int*)(DINVR + NPAD);
    int*   DEGR  = DEGC + NPAD;
    int*   CPTRC = DEGR + NPAD;
    int*   CURSC = CPTRC + NPAD;
    int*   CPTRR = CURSC + NPAD;
    int*   CURSR = CPTRR + NPAD;
    int*   BSUM  = CURSR + NPAD;
    int*   BOFF  = BSUM + 256;
    int*   SEGC  = BOFF + 256;          // 2*256*8 = 4096 ints
    float* WtU   = (float*)(SEGC + 4096);
    float* WtI   = WtU + DIM * DIM;
    int*   EDC   = (int*)(WtI + DIM * DIM);   // 2M int = 8 MB
    int*   EDR   = EDC + NUM_EDGES;
    int2*  BINBUF= (int2*)D;                  // 512*8*1152*8B = 37.75MB < 38.4MB

    const int BLOCKS = 2048, THREADS = 256;

    hipMemsetAsync(DEGC, 0, 2 * NPAD * sizeof(int), stream);
    transpose_w_kernel<<<1, 256, 0, stream>>>(W_user, W_item, WtU, WtI);

    // phase 1: ballot-binning into per-block private regions + deg histogram
    binphase1_kernel<<<2 * P1_BLKS_PER_B, 256, 0, stream>>>(
        cart_row, cart_col, rent_row, rent_col, DEGC, DEGR, SEGC, BINBUF);

    // dinv + colptr scans
    dinv2_kernel<<<(N_NODES + 255) / 256, 256, 0, stream>>>(DEGC, DEGR, DINVC, DINVR);
    scanA2_kernel<<<2 * SCAN_NBLK, SCAN_THREADS, 0, stream>>>(DEGC, DEGR, CPTRC, CPTRR, BSUM);
    scanB2_kernel<<<1, 64, 0, stream>>>(BSUM, BOFF, CPTRC, CPTRR);
    scanC2_kernel<<<2 * SCAN_NBLK, SCAN_THREADS, 0, stream>>>(CPTRC, CPTRR, CURSC, CURSR, BOFF);

    // phase 2: L2-local ticket scatter, 2 blocks per (behavior,bin)
    binphase2_kernel<<<32, 1024, 0, stream>>>(BINBUF, SEGC, CURSC, CURSR, EDC, EDR);

    // XS = dinvC * concat(user_emb, item_emb)
    prescale_kernel<<<BLOCKS, THREADS, 0, stream>>>((const float4*)user_emb,
                                                    (const float4*)item_emb,
                                                    DINVC, (float4*)A);

    // cart: H1 (B), HS = dinvC*H1 (C)
    conv1_kernel<<<CONV_GRID, 256, 0, stream>>>((const float4*)A, CPTRC, EDC,
                                                DINVC, (float4*)B, (float4*)C);
    // CART = (X + H1 + conv(HS)) / 3   (D -- BINBUF dead from here)
    conv2c_kernel<<<CONV_GRID, 256, 0, stream>>>((const float4*)C, CPTRC, EDC,
                                                 DINVC, (const float4*)B,
                                                 (const float4*)user_emb,
                                                 (const float4*)item_emb,
                                                 (float4*)D);

    // projection: X2 = CART @ W^T (A), XS2 = dinvR*X2 (B)
    matmul2_kernel<<<BLOCKS, THREADS, 0, stream>>>(D, WtU, WtI, DINVR, A, B);

    // rent: H1r -> d_out (parked), HSr -> C
    conv1_kernel<<<CONV_GRID, 256, 0, stream>>>((const float4*)B, CPTRR, EDR,
                                                DINVR, (float4*)out, (float4*)C);
    // out = CART + (X2 + H1r + conv(HSr)) / 3
    conv2r_kernel<<<CONV_GRID, 256, 0, stream>>>((const float4*)C, CPTRR, EDR,
                                                 DINVR, (const float4*)A,
                                                 (const float4*)D, (float4*)out);
}

// Round 12
// 930.371 us; speedup vs baseline: 1.1943x; 1.1934x over previous
//
#include <hip/hip_runtime.h>

#define NUM_USERS 100000
#define NUM_ITEMS 50000
#define N_NODES   150000   // NUM_USERS + NUM_ITEMS
#define DIM       64
#define NUM_EDGES 2000000
#define NPAD      150016

#define CONV_GRID ((N_NODES + 3) / 4)   // 4 nodes (waves) per 256-thr block

#define SCAN_THREADS 256
#define SCAN_ITEMS   8
#define SCAN_CHUNK   (SCAN_THREADS * SCAN_ITEMS)               // 2048
#define SCAN_NBLK    ((N_NODES + SCAN_CHUNK - 1) / SCAN_CHUNK) // 74

// ---------------------------------------------------------------------------
// Both behaviors' degree histograms in one pass (R6 lesson: atomics spread
// over 150K addresses are fine; never funnel onto few counters).
__global__ void hist2_kernel(const int* __restrict__ colC,
                             const int* __restrict__ colR,
                             int* __restrict__ degC,
                             int* __restrict__ degR) {
    int stride = gridDim.x * blockDim.x;
    for (int e = blockIdx.x * blockDim.x + threadIdx.x; e < NUM_EDGES; e += stride) {
        atomicAdd(&degC[colC[e]], 1);
        atomicAdd(&degR[colR[e]], 1);
    }
}

// dinv for both behaviors
__global__ void dinv2_kernel(const int* __restrict__ degC,
                             const int* __restrict__ degR,
                             float* __restrict__ dinvC,
                             float* __restrict__ dinvR) {
    int stride = gridDim.x * blockDim.x;
    for (int i = blockIdx.x * blockDim.x + threadIdx.x; i < N_NODES; i += stride) {
        float dc = (float)degC[i];
        float dr = (float)degR[i];
        dinvC[i] = (dc > 0.0f) ? (1.0f / sqrtf(dc)) : 0.0f;
        dinvR[i] = (dr > 0.0f) ? (1.0f / sqrtf(dr)) : 0.0f;
    }
}

// ---- exclusive scans (both behaviors fused; C = blocks [0,74), R = [74,148))
__global__ void scanA2_kernel(const int* __restrict__ degC,
                              const int* __restrict__ degR,
                              int* __restrict__ cptrC,
                              int* __restrict__ cptrR,
                              int* __restrict__ bsum) {
    __shared__ int s[SCAN_THREADS];
    bool isR = blockIdx.x >= SCAN_NBLK;
    int b = isR ? (int)blockIdx.x - SCAN_NBLK : (int)blockIdx.x;
    const int* deg = isR ? degR : degC;
    int* cptr = isR ? cptrR : cptrC;
    int t = threadIdx.x;
    int base = b * SCAN_CHUNK + t * SCAN_ITEMS;
    int items[SCAN_ITEMS];
    int mysum = 0;
    #pragma unroll
    for (int j = 0; j < SCAN_ITEMS; ++j) {
        int idx = base + j;
        items[j] = (idx < N_NODES) ? deg[idx] : 0;
        mysum += items[j];
    }
    s[t] = mysum;
    __syncthreads();
    for (int off = 1; off < SCAN_THREADS; off <<= 1) {
        int v = (t >= off) ? s[t - off] : 0;
        __syncthreads();
        s[t] += v;
        __syncthreads();
    }
    int excl = s[t] - mysum;
    if (t == SCAN_THREADS - 1) bsum[blockIdx.x] = s[t];
    int run = excl;
    #pragma unroll
    for (int j = 0; j < SCAN_ITEMS; ++j) {
        int idx = base + j;
        if (idx < N_NODES) cptr[idx] = run;
        run += items[j];
    }
}

__global__ void scanB2_kernel(const int* __restrict__ bsum,
                              int* __restrict__ boff,
                              int* __restrict__ cptrC,
                              int* __restrict__ cptrR) {
    if (threadIdx.x == 0) {
        int run = 0;
        for (int b = 0; b < SCAN_NBLK; ++b) { boff[b] = run; run += bsum[b]; }
        cptrC[N_NODES] = run;
    } else if (threadIdx.x == 1) {
        int run = 0;
        for (int b = SCAN_NBLK; b < 2 * SCAN_NBLK; ++b) { boff[b] = run; run += bsum[b]; }
        cptrR[N_NODES] = run;
    }
}

__global__ void scanC2_kernel(int* __restrict__ cptrC,
                              int* __restrict__ cptrR,
                              int* __restrict__ cursC,
                              int* __restrict__ cursR,
                              const int* __restrict__ boff) {
    bool isR = blockIdx.x >= SCAN_NBLK;
    int b = isR ? (int)blockIdx.x - SCAN_NBLK : (int)blockIdx.x;
    int* cptr = isR ? cptrR : cptrC;
    int* curs = isR ? cursR : cursC;
    int off = boff[blockIdx.x];
    int t = threadIdx.x;
    int base = b * SCAN_CHUNK + t * SCAN_ITEMS;
    #pragma unroll
    for (int j = 0; j < SCAN_ITEMS; ++j) {
        int idx = base + j;
        if (idx < N_NODES) {
            int v = cptr[idx] + off;
            cptr[idx] = v;
            curs[idx] = v;
        }
    }
}

// Simple ticket scatter, ONE behavior per launch (R12: splitting the R8
// fused scatter halves the concurrent write frontier; 4B payload halves
// bytes vs R4's int2. Four fancier schemes -- XCD-range, coarse bins,
// LDS bursts, private regions -- all measured WORSE than this).
__global__ void scatter_kernel(const int* __restrict__ row,
                               const int* __restrict__ col,
                               int* __restrict__ curs,
                               int* __restrict__ ed) {
    int stride = gridDim.x * blockDim.x;
    for (int e = blockIdx.x * blockDim.x + threadIdx.x; e < NUM_EDGES; e += stride) {
        int c = col[e];
        int p = atomicAdd(&curs[c], 1);
        ed[p] = row[e];
    }
}

// XS[i] = dinvC[node] * x0[i]
__global__ void prescale_kernel(const float4* __restrict__ ue,
                                const float4* __restrict__ ie,
                                const float* __restrict__ dinvC,
                                float4* __restrict__ xs) {
    int stride = gridDim.x * blockDim.x;
    const int n4 = N_NODES * 16;
    for (int i = blockIdx.x * blockDim.x + threadIdx.x; i < n4; i += stride) {
        int node = i >> 4;
        float d = dinvC[node];
        float4 v = (node < NUM_USERS) ? ue[i] : ie[i - NUM_USERS * 16];
        xs[i] = make_float4(d * v.x, d * v.y, d * v.z, d * v.w);
    }
}

// ---------------------------------------------------------------------------
// CSR gather conv (R8-verified): pure unweighted sum of pre-scaled rows,
// epilogue x dinv[node]. Wave = 1 node; 8 groups x 8 lanes, 8 edges in flight.
template <int MODE>
__device__ __forceinline__ void conv_body(int blk,
                                          const float4* __restrict__ xin,
                                          const int* __restrict__ colptr,
                                          const int* __restrict__ edata,
                                          const float* __restrict__ dinv,
                                          float4* o1,
                                          float4* __restrict__ o2,
                                          const float4* __restrict__ a0,
                                          const float4* __restrict__ a1,
                                          const float4* __restrict__ a2,
                                          const float4* __restrict__ ue,
                                          const float4* __restrict__ ie) {
    int lane = threadIdx.x & 63;
    int node = blk * 4 + (threadIdx.x >> 6);
    if (node >= N_NODES) return;
    int grp = lane >> 3;
    int l8  = lane & 7;
    int s = colptr[node];
    int t = colptr[node + 1];
    float4 acc0 = make_float4(0.f, 0.f, 0.f, 0.f);
    float4 acc1 = make_float4(0.f, 0.f, 0.f, 0.f);
    for (int e = s + grp; e < t; e += 8) {
        int r = edata[e];
        const float4* xp = xin + (size_t)r * 16 + l8 * 2;
        float4 v0 = xp[0];
        float4 v1 = xp[1];
        acc0.x += v0.x; acc0.y += v0.y; acc0.z += v0.z; acc0.w += v0.w;
        acc1.x += v1.x; acc1.y += v1.y; acc1.z += v1.z; acc1.w += v1.w;
    }
    #pragma unroll
    for (int m = 8; m <= 32; m <<= 1) {
        acc0.x += __shfl_xor(acc0.x, m); acc0.y += __shfl_xor(acc0.y, m);
        acc0.z += __shfl_xor(acc0.z, m); acc0.w += __shfl_xor(acc0.w, m);
        acc1.x += __shfl_xor(acc1.x, m); acc1.y += __shfl_xor(acc1.y, m);
        acc1.z += __shfl_xor(acc1.z, m); acc1.w += __shfl_xor(acc1.w, m);
    }
    if (grp == 0) {
        float dc = dinv[node];
        int o = node * 16 + l8 * 2;
        if (MODE == 0) {
            float d2 = dc * dc;
            o1[o]     = make_float4(dc * acc0.x, dc * acc0.y, dc * acc0.z, dc * acc0.w);
            o1[o + 1] = make_float4(dc * acc1.x, dc * acc1.y, dc * acc1.z, dc * acc1.w);
            o2[o]     = make_float4(d2 * acc0.x, d2 * acc0.y, d2 * acc0.z, d2 * acc0.w);
            o2[o + 1] = make_float4(d2 * acc1.x, d2 * acc1.y, d2 * acc1.z, d2 * acc1.w);
        } else if (MODE == 1) {
            const float sc = 1.0f / 3.0f;
            float4 x0, x1;
            if (node < NUM_USERS) { x0 = ue[o]; x1 = ue[o + 1]; }
            else { x0 = ie[o - NUM_USERS * 16]; x1 = ie[o + 1 - NUM_USERS * 16]; }
            float4 h0 = a1[o], h1 = a1[o + 1];
            o1[o]     = make_float4((x0.x + h0.x + dc * acc0.x) * sc,
                                    (x0.y + h0.y + dc * acc0.y) * sc,
                                    (x0.z + h0.z + dc * acc0.z) * sc,
                                    (x0.w + h0.w + dc * acc0.w) * sc);
            o1[o + 1] = make_float4((x1.x + h1.x + dc * acc1.x) * sc,
                                    (x1.y + h1.y + dc * acc1.y) * sc,
                                    (x1.z + h1.z + dc * acc1.z) * sc,
                                    (x1.w + h1.w + dc * acc1.w) * sc);
        } else {
            const float sc = 1.0f / 3.0f;
            float4 p0 = a0[o], p1 = a0[o + 1];
            float4 h0 = o1[o], h1 = o1[o + 1];    // H1r parked in d_out
            float4 g0 = a2[o], g1 = a2[o + 1];
            o1[o]     = make_float4(g0.x + (p0.x + h0.x + dc * acc0.x) * sc,
                                    g0.y + (p0.y + h0.y + dc * acc0.y) * sc,
                                    g0.z + (p0.z + h0.z + dc * acc0.z) * sc,
                                    g0.w + (p0.w + h0.w + dc * acc0.w) * sc);
            o1[o + 1] = make_float4(g1.x + (p1.x + h1.x + dc * acc1.x) * sc,
                                    g1.y + (p1.y + h1.y + dc * acc1.y) * sc,
                                    g1.z + (p1.z + h1.z + dc * acc1.z) * sc,
                                    g1.w + (p1.w + h1.w + dc * acc1.w) * sc);
        }
    }
}

__global__ void conv1_kernel(const float4* __restrict__ xin,
                             const int* __restrict__ colptr,
                             const int* __restrict__ edata,
                             const float* __restrict__ dinv,
                             float4* __restrict__ oH,
                             float4* __restrict__ oHS) {
    conv_body<0>(blockIdx.x, xin, colptr, edata, dinv, oH, oHS,
                 nullptr, nullptr, nullptr, nullptr, nullptr);
}

__global__ void conv2c_kernel(const float4* __restrict__ xin,
                              const int* __restrict__ colptr,
                              const int* __restrict__ edata,
                              const float* __restrict__ dinv,
                              const float4* __restrict__ h1,
                              const float4* __restrict__ ue,
                              const float4* __restrict__ ie,
                              float4* __restrict__ cart) {
    conv_body<1>(blockIdx.x, xin, colptr, edata, dinv, cart, nullptr,
                 nullptr, h1, nullptr, ue, ie);
}

__global__ void conv2r_kernel(const float4* __restrict__ xin,
                              const int* __restrict__ colptr,
                              const int* __restrict__ edata,
                              const float* __restrict__ dinv,
                              const float4* __restrict__ x2,
                              const float4* __restrict__ cart,
                              float4* outp) {
    conv_body<2>(blockIdx.x, xin, colptr, edata, dinv, outp, nullptr,
                 x2, nullptr, cart, nullptr, nullptr);
}

// Wt[k][j] = W[j][k]
__global__ void transpose_w_kernel(const float* __restrict__ Wu,
                                   const float* __restrict__ Wi,
                                   float* __restrict__ WtU,
                                   float* __restrict__ WtI) {
    for (int t = threadIdx.x; t < DIM * DIM; t += blockDim.x) {
        int j = t >> 6, k = t & 63;
        WtU[k * DIM + j] = Wu[t];
        WtI[k * DIM + j] = Wi[t];
    }
}

// dst = src @ Wt (per-row user/item); dsts = dinvR[i] * dst
__global__ void matmul2_kernel(const float* __restrict__ src,
                               const float* __restrict__ WtU,
                               const float* __restrict__ WtI,
                               const float* __restrict__ dinvR,
                               float* __restrict__ dst,
                               float* __restrict__ dsts) {
    __shared__ float rows[4][DIM];
    int lane = threadIdx.x & 63;
    int g = threadIdx.x >> 6;
    int totalGroups = N_NODES / 4;
    for (int blk = blockIdx.x; blk < totalGroups; blk += gridDim.x) {
        int i = blk * 4 + g;
        rows[g][lane] = src[(size_t)i * DIM + lane];
        __syncthreads();
        const float* Wt = (i < NUM_USERS) ? WtU : WtI;
        float acc = 0.0f;
        #pragma unroll
        for (int k = 0; k < DIM; ++k)
            acc = fmaf(rows[g][k], Wt[k * DIM + lane], acc);
        dst[(size_t)i * DIM + lane]  = acc;
        dsts[(size_t)i * DIM + lane] = dinvR[i] * acc;
        __syncthreads();
    }
}

// ---------------------------------------------------------------------------
extern "C" void kernel_launch(void* const* d_in, const int* in_sizes, int n_in,
                              void* d_out, int out_size, void* d_ws, size_t ws_size,
                              hipStream_t stream) {
    const float* user_emb = (const float*)d_in[0];
    const float* item_emb = (const float*)d_in[1];
    const float* W_user   = (const float*)d_in[2];
    const float* W_item   = (const float*)d_in[3];
    const int*   ec       = (const int*)d_in[4];
    const int*   er       = (const int*)d_in[5];
    const int* cart_row = ec;
    const int* cart_col = ec + NUM_EDGES;
    const int* rent_row = er;
    const int* rent_col = er + NUM_EDGES;
    float* out = (float*)d_out;

    const size_t NV = (size_t)N_NODES * DIM;       // 9.6M floats
    float* ws    = (float*)d_ws;
    float* A     = ws;                  // XS, then X2 after matmul
    float* B     = A + NV;              // H1 (cart), then XS2
    float* C     = B + NV;              // HS (cart), then HSr (rent)
    float* D     = C + NV;              // CART
    float* DINVC = D + NV;
    float* DINVR = DINVC + NPAD;
    int*   DEGC  = (int*)(DINVR + NPAD);
    int*   DEGR  = DEGC + NPAD;         // adjacent -> one memset covers both
    int*   CPTRC = DEGR + NPAD;
    int*   CURSC = CPTRC + NPAD;
    int*   CPTRR = CURSC + NPAD;
    int*   CURSR = CPTRR + NPAD;
    int*   BSUM  = CURSR + NPAD;
    int*   BOFF  = BSUM + 256;
    float* WtU   = (float*)(BOFF + 256);
    float* WtI   = WtU + DIM * DIM;
    int*   EDC   = (int*)(WtI + DIM * DIM);   // 2M int = 8 MB
    int*   EDR   = EDC + NUM_EDGES;

    const int BLOCKS = 2048, THREADS = 256;

    hipMemsetAsync(DEGC, 0, 2 * NPAD * sizeof(int), stream);
    transpose_w_kernel<<<1, 256, 0, stream>>>(W_user, W_item, WtU, WtI);

    // CSR build: fused histograms, fused scans, SEPARATE per-behavior scatters
    hist2_kernel<<<BLOCKS, THREADS, 0, stream>>>(cart_col, rent_col, DEGC, DEGR);
    dinv2_kernel<<<(N_NODES + 255) / 256, 256, 0, stream>>>(DEGC, DEGR, DINVC, DINVR);
    scanA2_kernel<<<2 * SCAN_NBLK, SCAN_THREADS, 0, stream>>>(DEGC, DEGR, CPTRC, CPTRR, BSUM);
    scanB2_kernel<<<1, 64, 0, stream>>>(BSUM, BOFF, CPTRC, CPTRR);
    scanC2_kernel<<<2 * SCAN_NBLK, SCAN_THREADS, 0, stream>>>(CPTRC, CPTRR, CURSC, CURSR, BOFF);
    scatter_kernel<<<BLOCKS, THREADS, 0, stream>>>(cart_row, cart_col, CURSC, EDC);
    scatter_kernel<<<BLOCKS, THREADS, 0, stream>>>(rent_row, rent_col, CURSR, EDR);

    // XS = dinvC * concat(user_emb, item_emb)
    prescale_kernel<<<BLOCKS, THREADS, 0, stream>>>((const float4*)user_emb,
                                                    (const float4*)item_emb,
                                                    DINVC, (float4*)A);

    // cart: H1 (B), HS = dinvC*H1 (C)
    conv1_kernel<<<CONV_GRID, 256, 0, stream>>>((const float4*)A, CPTRC, EDC,
                                                DINVC, (float4*)B, (float4*)C);
    // CART = (X + H1 + conv(HS)) / 3
    conv2c_kernel<<<CONV_GRID, 256, 0, stream>>>((const float4*)C, CPTRC, EDC,
                                                 DINVC, (const float4*)B,
                                                 (const float4*)user_emb,
                                                 (const float4*)item_emb,
                                                 (float4*)D);

    // projection: X2 = CART @ W^T (A), XS2 = dinvR*X2 (B)
    matmul2_kernel<<<BLOCKS, THREADS, 0, stream>>>(D, WtU, WtI, DINVR, A, B);

    // rent: H1r -> d_out (parked), HSr -> C
    conv1_kernel<<<CONV_GRID, 256, 0, stream>>>((const float4*)B, CPTRR, EDR,
                                                DINVR, (float4*)out, (float4*)C);
    // out = CART + (X2 + H1r + conv(HSr)) / 3
    conv2r_kernel<<<CONV_GRID, 256, 0, stream>>>((const float4*)C, CPTRR, EDR,
                                                 DINVR, (const float4*)A,
                                                 (const float4*)D, (float4*)out);
}